// Round 2
// baseline (374.827 us; speedup 1.0000x reference)
//
#include <hip/hip_runtime.h>
#include <hip/hip_bf16.h>

#define ADAPTERS 40
#define CAPS 3
#define IN_CH 600
#define BSZ 256
#define DCLS 200
#define DMODEL 768

typedef float v2f __attribute__((ext_vector_type(2)));

// ---------------------------------------------------------------------------
// K0: gw4[j] = (g*lw[j][0], g*lw[j][1], g*lw[j][2], g*lb[j]),
//     g = sigmoid(s * elarger[t][j])
// ---------------------------------------------------------------------------
__global__ void k0_gw(const float* __restrict__ s_p,
                      const float* __restrict__ lw,
                      const float* __restrict__ lb,
                      const float* __restrict__ el,
                      const int* __restrict__ t_p,
                      float4* __restrict__ gw4) {
    int j = blockIdx.x * blockDim.x + threadIdx.x;
    if (j >= DMODEL) return;
    float s = s_p[0];
    int t = t_p[0];
    float e = el[t * DMODEL + j];
    float g = 1.0f / (1.0f + expf(-s * e));
    gw4[j] = make_float4(g * lw[j * 3 + 0], g * lw[j * 3 + 1],
                         g * lw[j * 3 + 2], g * lb[j]);
}

// ---------------------------------------------------------------------------
// K1: priors[n][b][k][d] = sum_c x[b][k][c] * rw[k][n][c][d]   (f32)
// One block = 128(b) x 128(d) tile of one (k,n) pair; 256 thr as 16x16,
// 8x8 accumulators per thread, split 4+4 so LDS float4 reads are <=2-way.
// Inactive adapters (tsv[t][k]==0) exit — never read downstream.
// ---------------------------------------------------------------------------
#define MT 128
#define NT 128
#define KC 24
#define LDP 132   // LDS row pitch (floats)

__global__ __launch_bounds__(256) void k1_priors(
    const float* __restrict__ x,    // [B][A][IN_CH]
    const float* __restrict__ rw,   // [A][CAPS][IN_CH][DCLS]
    const float* __restrict__ tsv,  // [A][A]
    const int* __restrict__ t_p,
    float* __restrict__ priors)     // [CAPS][B][A][DCLS]
{
    int pair = blockIdx.z;          // 0..119
    int k = pair / 3, n = pair % 3;
    int t = t_p[0];
    if (tsv[t * ADAPTERS + k] == 0.0f) return;

    int b0 = blockIdx.x * MT;
    int d0 = blockIdx.y * NT;

    __shared__ __align__(16) float xs[KC * LDP];
    __shared__ __align__(16) float wsh[KC * LDP];

    int tid = threadIdx.x;
    int tx = tid & 15, ty = tid >> 4;

    v2f acc[8][4];
    #pragma unroll
    for (int r = 0; r < 8; r++)
        #pragma unroll
        for (int c = 0; c < 4; c++) { acc[r][c].x = 0.f; acc[r][c].y = 0.f; }

    const float* xbase = x + k * IN_CH;
    const float* wbase = rw + (size_t)(k * 3 + n) * IN_CH * DCLS;

    for (int q = 0; q < IN_CH / KC; q++) {
        int c0 = q * KC;
        // stage x: 128 b x 24 c (float2 loads, transposed into xs[c][b])
        #pragma unroll
        for (int l = 0; l < 6; l++) {
            int idx = l * 256 + tid;           // 0..1535
            int bi = idx / 12;                 // 0..127
            int c2 = (idx % 12) * 2;           // 0..22 even
            const float* p =
                xbase + (size_t)(b0 + bi) * (ADAPTERS * IN_CH) + c0 + c2;
            float2 v = *(const float2*)p;
            xs[(c2 + 0) * LDP + bi] = v.x;
            xs[(c2 + 1) * LDP + bi] = v.y;
        }
        // stage w: 24 c x 128 d (d>=200 zero-filled)
        #pragma unroll
        for (int l = 0; l < 6; l++) {
            int idx = l * 256 + tid;           // 0..1535
            int cj = idx / 64;                 // 0..23
            int dd = (idx % 64) * 2;           // 0..126 even
            float f0 = 0.f, f1 = 0.f;
            int d = d0 + dd;
            if (d < DCLS) {
                float2 v = *(const float2*)(wbase + (size_t)(c0 + cj) * DCLS + d);
                f0 = v.x;
                f1 = v.y;
            }
            wsh[cj * LDP + dd] = f0;
            wsh[cj * LDP + dd + 1] = f1;
        }
        __syncthreads();
        #pragma unroll
        for (int j = 0; j < KC; j++) {
            float4 xa = *(const float4*)(xs + j * LDP + ty * 4);
            float4 xc = *(const float4*)(xs + j * LDP + 64 + ty * 4);
            float4 wa = *(const float4*)(wsh + j * LDP + tx * 4);
            float4 wc = *(const float4*)(wsh + j * LDP + 64 + tx * 4);
            v2f w01, w23, w45, w67;
            w01.x = wa.x; w01.y = wa.y;  w23.x = wa.z; w23.y = wa.w;
            w45.x = wc.x; w45.y = wc.y;  w67.x = wc.z; w67.y = wc.w;
            float xr[8] = {xa.x, xa.y, xa.z, xa.w, xc.x, xc.y, xc.z, xc.w};
            #pragma unroll
            for (int r = 0; r < 8; r++) {
                v2f xv; xv.x = xr[r]; xv.y = xr[r];
                acc[r][0] += xv * w01;
                acc[r][1] += xv * w23;
                acc[r][2] += xv * w45;
                acc[r][3] += xv * w67;
            }
        }
        __syncthreads();
    }
    #pragma unroll
    for (int r = 0; r < 8; r++) {
        int b = b0 + ((r < 4) ? (ty * 4 + r) : (64 + ty * 4 + (r - 4)));
        float* outp = priors + ((size_t)(n * BSZ + b) * ADAPTERS + k) * DCLS;
        int d1 = d0 + tx * 4;
        if (d1 + 3 < DCLS) {
            *(float4*)(outp + d1) = make_float4(acc[r][0].x, acc[r][0].y,
                                                acc[r][1].x, acc[r][1].y);
        }
        int d2 = d0 + 64 + tx * 4;
        if (d2 + 3 < DCLS) {
            *(float4*)(outp + d2) = make_float4(acc[r][2].x, acc[r][2].y,
                                                acc[r][3].x, acc[r][3].y);
        }
    }
}

// ---------------------------------------------------------------------------
// K2: dynamic routing, one block per (n,b); P[k][d] staged in LDS.
// Final (unsquashed) vote written flat [n][b][d].
// ---------------------------------------------------------------------------
__global__ __launch_bounds__(256) void k2_route(
    const float* __restrict__ priors,   // [CAPS][B][A][DCLS]
    const float* __restrict__ tsv,
    const int* __restrict__ t_p,
    float* __restrict__ vote)           // [CAPS][B][DCLS]
{
    int nb = blockIdx.x;                // 0..767
    int n = nb >> 8, b = nb & 255;
    int tid = threadIdx.x;
    int lane = tid & 63, wid = tid >> 6;

    __shared__ float Ps[ADAPTERS * DCLS];   // 32 KB
    __shared__ float vout[DCLS];
    __shared__ float a_s[ADAPTERS];
    __shared__ float probs_s[ADAPTERS];
    __shared__ float act[ADAPTERS];
    __shared__ float red[4];
    __shared__ float scl;

    int t = t_p[0];
    if (tid < ADAPTERS) {
        act[tid] = tsv[t * ADAPTERS + tid];
        a_s[tid] = 0.0f;
    }
    __syncthreads();

    const float* pb = priors + (size_t)(n * BSZ + b) * ADAPTERS * DCLS;
    for (int idx = tid; idx < ADAPTERS * DCLS; idx += 256) {
        int k = idx / DCLS;
        if (act[k] != 0.0f) Ps[idx] = pb[idx];
    }
    __syncthreads();

    float cnt = 0.0f;
    for (int k = 0; k < ADAPTERS; k++) cnt += (act[k] != 0.f) ? 1.f : 0.f;

    int td = tid;
    float v = 0.0f;
    if (td < DCLS) {
        for (int k = 0; k < ADAPTERS; k++)
            if (act[k] != 0.f) v += Ps[k * DCLS + td];
        v /= cnt;
    }

    for (int it = 0; it < 3; it++) {
        if (it > 0) {
            if (wid == 0) {
                bool on = (lane < ADAPTERS) && (act[lane] != 0.f);
                float val = on ? a_s[lane] : -3.0e38f;
                float m = val;
                for (int off = 32; off; off >>= 1)
                    m = fmaxf(m, __shfl_down(m, off));
                m = __shfl(m, 0);
                float e = on ? expf(val - m) : 0.f;
                float ssum = e;
                for (int off = 32; off; off >>= 1)
                    ssum += __shfl_down(ssum, off);
                ssum = __shfl(ssum, 0);
                if (lane < ADAPTERS) probs_s[lane] = e / ssum;
            }
            __syncthreads();
            v = 0.0f;
            if (td < DCLS) {
                for (int k = 0; k < ADAPTERS; k++)
                    if (act[k] != 0.f) v += probs_s[k] * Ps[k * DCLS + td];
            }
        }
        if (it == 2) break;

        float vv = (td < DCLS) ? v * v : 0.f;
        for (int off = 32; off; off >>= 1) vv += __shfl_down(vv, off);
        if (lane == 0) red[wid] = vv;
        __syncthreads();
        if (tid == 0) {
            float sq = red[0] + red[1] + red[2] + red[3];
            scl = sqrtf(sq) / (1.0f + sq);
        }
        __syncthreads();
        if (td < DCLS) vout[td] = v * scl;
        __syncthreads();

        for (int k = wid; k < ADAPTERS; k += 4) {
            if (act[k] == 0.f) continue;
            const float* row = Ps + k * DCLS;
            float p = row[lane] * vout[lane]
                    + row[lane + 64] * vout[lane + 64]
                    + row[lane + 128] * vout[lane + 128];
            if (lane < DCLS - 192) p += row[lane + 192] * vout[lane + 192];
            for (int off = 32; off; off >>= 1) p += __shfl_down(p, off);
            if (lane == 0) a_s[k] += p;
        }
        __syncthreads();
    }

    if (td < DCLS) vote[(size_t)n * BSZ * DCLS + b * DCLS + td] = v;
}

// ---------------------------------------------------------------------------
// K3: out[row][j] = sum_c vote_flat[row*3+c]*gw4[j].c + gw4[j].w
// (reshape scramble is free: vote stored flat [n][b][d] == row-major (b,d,n))
// ---------------------------------------------------------------------------
__global__ __launch_bounds__(384) void k3_out(
    const float* __restrict__ vote,     // [3*256*200] flat
    const float4* __restrict__ gw4,     // [768]
    float* __restrict__ out)            // [256*200][768]
{
    int row = blockIdx.x;               // 0..51199
    int tid = threadIdx.x;              // 0..383
    __shared__ float h[3];
    if (tid < 3) h[tid] = vote[row * 3 + tid];
    __syncthreads();
    float h0 = h[0], h1 = h[1], h2 = h[2];
    float* o = out + (size_t)row * DMODEL;
    int j = tid * 2;
    float4 ga = gw4[j];
    float4 gb = gw4[j + 1];
    float2 pack;
    pack.x = h0 * ga.x + h1 * ga.y + h2 * ga.z + ga.w;
    pack.y = h0 * gb.x + h1 * gb.y + h2 * gb.z + gb.w;
    *(float2*)(o + j) = pack;
}

// ---------------------------------------------------------------------------
extern "C" void kernel_launch(void* const* d_in, const int* in_sizes, int n_in,
                              void* d_out, int out_size, void* d_ws, size_t ws_size,
                              hipStream_t stream) {
    const int*   t   = (const int*)d_in[0];
    const float* x   = (const float*)d_in[1];
    const float* s   = (const float*)d_in[2];
    const float* rw  = (const float*)d_in[3];
    const float* lw  = (const float*)d_in[4];
    const float* lb  = (const float*)d_in[5];
    const float* el  = (const float*)d_in[6];
    const float* tsv = (const float*)d_in[7];
    float* out = (float*)d_out;

    char* wsb = (char*)d_ws;
    float*  priors = (float*)wsb;                // 3*256*40*200 f32 = 24,576,000 B
    float*  vote   = (float*)(wsb + 24576000);   // 3*256*200 f32
    float4* gw4    = (float4*)(wsb + 25190400);  // 768 float4

    k0_gw<<<dim3(3), dim3(256), 0, stream>>>(s, lw, lb, el, t, gw4);
    k1_priors<<<dim3(2, 2, 120), dim3(256), 0, stream>>>(x, rw, tsv, t, priors);
    k2_route<<<dim3(CAPS * BSZ), dim3(256), 0, stream>>>(priors, tsv, t, vote);
    k3_out<<<dim3(BSZ * DCLS), dim3(384), 0, stream>>>(vote, gw4, out);
}

// Round 3
// 371.999 us; speedup vs baseline: 1.0076x; 1.0076x over previous
//
#include <hip/hip_runtime.h>
#include <hip/hip_bf16.h>

#define ADAPTERS 40
#define CAPS 3
#define IN_CH 600
#define BSZ 256
#define DCLS 200
#define DMODEL 768

// ---------------------------------------------------------------------------
// K0: gw4[j] = (g*lw[j][0], g*lw[j][1], g*lw[j][2], g*lb[j]),
//     g = sigmoid(s * elarger[t][j])
// ---------------------------------------------------------------------------
__global__ void k0_gw(const float* __restrict__ s_p,
                      const float* __restrict__ lw,
                      const float* __restrict__ lb,
                      const float* __restrict__ el,
                      const int* __restrict__ t_p,
                      float4* __restrict__ gw4) {
    int j = blockIdx.x * blockDim.x + threadIdx.x;
    if (j >= DMODEL) return;
    float s = s_p[0];
    int t = t_p[0];
    float e = el[t * DMODEL + j];
    float g = 1.0f / (1.0f + expf(-s * e));
    gw4[j] = make_float4(g * lw[j * 3 + 0], g * lw[j * 3 + 1],
                         g * lw[j * 3 + 2], g * lb[j]);
}

// ---------------------------------------------------------------------------
// K1: priors[n][b][k][d] = sum_c x[b][k][c] * rw[k][n][c][d]   (f32)
// Caps folded into N: per adapter k, GEMM M=256(b) x N=640(j=(cap,d) padded)
// x K=600(c). Block tile 64(M) x 128(N), 256 thr as 16(ty:m)x16(tx:n),
// 4x8 acc/thread. 21 active k x 4 x 5 = 420 blocks.
// j -> (cap = j/200, d = j%200); j>=600 is pad (zero B, masked store).
// float4 stores legal: 200 % 4 == 0 so an aligned j-quad never crosses a cap.
// ---------------------------------------------------------------------------
#define KC 24
#define XPITCH 68    // xs row pitch (floats)
#define WPITCH 132   // ws row pitch (floats)

__global__ __launch_bounds__(256) void k1_priors(
    const float* __restrict__ x,    // [B][A][IN_CH]
    const float* __restrict__ rw,   // [A][CAPS][IN_CH][DCLS]
    const float* __restrict__ tsv,  // [A][A]
    const int* __restrict__ t_p,
    float* __restrict__ priors)     // [CAPS][B][A][DCLS]
{
    int k = blockIdx.z;             // adapter
    int t = t_p[0];
    if (tsv[t * ADAPTERS + k] == 0.0f) return;

    int b0 = blockIdx.x * 64;       // 0..192
    int j0 = blockIdx.y * 128;      // 0,128,256,384,512

    __shared__ __align__(16) float xs[KC * XPITCH];  // [c][b]  6.5 KB
    __shared__ __align__(16) float ws[KC * WPITCH];  // [c][j] 12.7 KB

    int tid = threadIdx.x;
    int tx = tid & 15, ty = tid >> 4;

    float acc[4][8];
    #pragma unroll
    for (int r = 0; r < 4; r++)
        #pragma unroll
        for (int c = 0; c < 8; c++) acc[r][c] = 0.f;

    const float* xbase = x + k * IN_CH;
    const float* wbase = rw + (size_t)k * 3 * IN_CH * DCLS;

    for (int q = 0; q < IN_CH / KC; q++) {
        int c0 = q * KC;
        // stage x: 64 b x 24 c (float2 loads, transposed into xs[c][b])
        #pragma unroll
        for (int l = 0; l < 3; l++) {
            int idx = l * 256 + tid;           // 0..767
            int bi = idx / 12;                 // 0..63
            int c2 = (idx % 12) * 2;           // 0..22 even
            const float* p =
                xbase + (size_t)(b0 + bi) * (ADAPTERS * IN_CH) + c0 + c2;
            float2 v = *(const float2*)p;
            xs[(c2 + 0) * XPITCH + bi] = v.x;
            xs[(c2 + 1) * XPITCH + bi] = v.y;
        }
        // stage w: 24 c x 128 j  (scalar f32 loads, coalesced in d-runs)
        #pragma unroll
        for (int l = 0; l < 12; l++) {
            int idx = l * 256 + tid;           // 0..3071
            int cj = idx >> 7;                 // 0..23
            int jj = idx & 127;                // 0..127
            int j = j0 + jj;
            float val = 0.f;
            if (j < CAPS * DCLS) {
                int cap = j / DCLS;
                int d = j - cap * DCLS;
                val = wbase[((size_t)cap * IN_CH + (c0 + cj)) * DCLS + d];
            }
            ws[cj * WPITCH + jj] = val;
        }
        __syncthreads();
        #pragma unroll
        for (int jstep = 0; jstep < KC; jstep++) {
            float4 xa = *(const float4*)(xs + jstep * XPITCH + ty * 4);
            float4 w0 = *(const float4*)(ws + jstep * WPITCH + tx * 4);
            float4 w1 = *(const float4*)(ws + jstep * WPITCH + 64 + tx * 4);
            float xr[4] = {xa.x, xa.y, xa.z, xa.w};
            float wc[8] = {w0.x, w0.y, w0.z, w0.w, w1.x, w1.y, w1.z, w1.w};
            #pragma unroll
            for (int r = 0; r < 4; r++)
                #pragma unroll
                for (int c = 0; c < 8; c++)
                    acc[r][c] += xr[r] * wc[c];
        }
        __syncthreads();
    }
    // store: two float4 per m-row, masked to j<600
    #pragma unroll
    for (int r = 0; r < 4; r++) {
        int b = b0 + ty * 4 + r;
        int j1 = j0 + tx * 4;
        if (j1 < CAPS * DCLS) {
            int cap = j1 / DCLS, d = j1 - cap * DCLS;
            float* outp = priors + ((size_t)(cap * BSZ + b) * ADAPTERS + k) * DCLS + d;
            *(float4*)outp = make_float4(acc[r][0], acc[r][1], acc[r][2], acc[r][3]);
        }
        int j2 = j0 + 64 + tx * 4;
        if (j2 < CAPS * DCLS) {
            int cap = j2 / DCLS, d = j2 - cap * DCLS;
            float* outp = priors + ((size_t)(cap * BSZ + b) * ADAPTERS + k) * DCLS + d;
            *(float4*)outp = make_float4(acc[r][4], acc[r][5], acc[r][6], acc[r][7]);
        }
    }
}

// ---------------------------------------------------------------------------
// K2: dynamic routing, one block per (n,b); P[k][d] staged in LDS.
// Final (unsquashed) vote written flat [n][b][d].
// ---------------------------------------------------------------------------
__global__ __launch_bounds__(256) void k2_route(
    const float* __restrict__ priors,   // [CAPS][B][A][DCLS]
    const float* __restrict__ tsv,
    const int* __restrict__ t_p,
    float* __restrict__ vote)           // [CAPS][B][DCLS]
{
    int nb = blockIdx.x;                // 0..767
    int n = nb >> 8, b = nb & 255;
    int tid = threadIdx.x;
    int lane = tid & 63, wid = tid >> 6;

    __shared__ float Ps[ADAPTERS * DCLS];   // 32 KB
    __shared__ float vout[DCLS];
    __shared__ float a_s[ADAPTERS];
    __shared__ float probs_s[ADAPTERS];
    __shared__ float act[ADAPTERS];
    __shared__ float red[4];
    __shared__ float scl;

    int t = t_p[0];
    if (tid < ADAPTERS) {
        act[tid] = tsv[t * ADAPTERS + tid];
        a_s[tid] = 0.0f;
    }
    __syncthreads();

    const float* pb = priors + (size_t)(n * BSZ + b) * ADAPTERS * DCLS;
    for (int idx = tid; idx < ADAPTERS * DCLS; idx += 256) {
        int k = idx / DCLS;
        if (act[k] != 0.0f) Ps[idx] = pb[idx];
    }
    __syncthreads();

    float cnt = 0.0f;
    for (int k = 0; k < ADAPTERS; k++) cnt += (act[k] != 0.f) ? 1.f : 0.f;

    int td = tid;
    float v = 0.0f;
    if (td < DCLS) {
        for (int k = 0; k < ADAPTERS; k++)
            if (act[k] != 0.f) v += Ps[k * DCLS + td];
        v /= cnt;
    }

    for (int it = 0; it < 3; it++) {
        if (it > 0) {
            if (wid == 0) {
                bool on = (lane < ADAPTERS) && (act[lane] != 0.f);
                float val = on ? a_s[lane] : -3.0e38f;
                float m = val;
                for (int off = 32; off; off >>= 1)
                    m = fmaxf(m, __shfl_down(m, off));
                m = __shfl(m, 0);
                float e = on ? expf(val - m) : 0.f;
                float ssum = e;
                for (int off = 32; off; off >>= 1)
                    ssum += __shfl_down(ssum, off);
                ssum = __shfl(ssum, 0);
                if (lane < ADAPTERS) probs_s[lane] = e / ssum;
            }
            __syncthreads();
            v = 0.0f;
            if (td < DCLS) {
                for (int k = 0; k < ADAPTERS; k++)
                    if (act[k] != 0.f) v += probs_s[k] * Ps[k * DCLS + td];
            }
        }
        if (it == 2) break;

        float vv = (td < DCLS) ? v * v : 0.f;
        for (int off = 32; off; off >>= 1) vv += __shfl_down(vv, off);
        if (lane == 0) red[wid] = vv;
        __syncthreads();
        if (tid == 0) {
            float sq = red[0] + red[1] + red[2] + red[3];
            scl = sqrtf(sq) / (1.0f + sq);
        }
        __syncthreads();
        if (td < DCLS) vout[td] = v * scl;
        __syncthreads();

        for (int k = wid; k < ADAPTERS; k += 4) {
            if (act[k] == 0.f) continue;
            const float* row = Ps + k * DCLS;
            float p = row[lane] * vout[lane]
                    + row[lane + 64] * vout[lane + 64]
                    + row[lane + 128] * vout[lane + 128];
            if (lane < DCLS - 192) p += row[lane + 192] * vout[lane + 192];
            for (int off = 32; off; off >>= 1) p += __shfl_down(p, off);
            if (lane == 0) a_s[k] += p;
        }
        __syncthreads();
    }

    if (td < DCLS) vote[(size_t)n * BSZ * DCLS + b * DCLS + td] = v;
}

// ---------------------------------------------------------------------------
// K3: out[row][j] = sum_c vote_flat[row*3+c]*gw4[j].c + gw4[j].w
// Column-stationary: each thread owns 4 fixed cols (gw4 in regs), loops
// 16 rows; coalesced float4 stores (1 KB/wave). 2400 blocks.
// ---------------------------------------------------------------------------
__global__ __launch_bounds__(256) void k3_out(
    const float* __restrict__ vote,     // [3*256*200] flat
    const float4* __restrict__ gw4,     // [768]
    float* __restrict__ out)            // [51200][768]
{
    int lane = threadIdx.x & 63;
    int ty = threadIdx.x >> 6;          // 0..3
    int j = blockIdx.y * 256 + lane * 4;   // 4 consecutive cols
    int r0 = blockIdx.x * 64;              // 64 rows per block

    float4 g0 = gw4[j + 0];
    float4 g1 = gw4[j + 1];
    float4 g2 = gw4[j + 2];
    float4 g3 = gw4[j + 3];

    for (int it = 0; it < 16; it++) {
        int row = r0 + it * 4 + ty;
        float h0 = vote[row * 3 + 0];
        float h1 = vote[row * 3 + 1];
        float h2 = vote[row * 3 + 2];
        float4 o;
        o.x = h0 * g0.x + h1 * g0.y + h2 * g0.z + g0.w;
        o.y = h0 * g1.x + h1 * g1.y + h2 * g1.z + g1.w;
        o.z = h0 * g2.x + h1 * g2.y + h2 * g2.z + g2.w;
        o.w = h0 * g3.x + h1 * g3.y + h2 * g3.z + g3.w;
        *(float4*)(out + (size_t)row * DMODEL + j) = o;
    }
}

// ---------------------------------------------------------------------------
extern "C" void kernel_launch(void* const* d_in, const int* in_sizes, int n_in,
                              void* d_out, int out_size, void* d_ws, size_t ws_size,
                              hipStream_t stream) {
    const int*   t   = (const int*)d_in[0];
    const float* x   = (const float*)d_in[1];
    const float* s   = (const float*)d_in[2];
    const float* rw  = (const float*)d_in[3];
    const float* lw  = (const float*)d_in[4];
    const float* lb  = (const float*)d_in[5];
    const float* el  = (const float*)d_in[6];
    const float* tsv = (const float*)d_in[7];
    float* out = (float*)d_out;

    char* wsb = (char*)d_ws;
    float*  priors = (float*)wsb;                // 3*256*40*200 f32 = 24,576,000 B
    float*  vote   = (float*)(wsb + 24576000);   // 3*256*200 f32
    float4* gw4    = (float4*)(wsb + 25190400);  // 768 float4

    k0_gw<<<dim3(3), dim3(256), 0, stream>>>(s, lw, lb, el, t, gw4);
    k1_priors<<<dim3(4, 5, ADAPTERS), dim3(256), 0, stream>>>(x, rw, tsv, t, priors);
    k2_route<<<dim3(CAPS * BSZ), dim3(256), 0, stream>>>(priors, tsv, t, vote);
    k3_out<<<dim3(BSZ * DCLS / 64, 3), dim3(256), 0, stream>>>(vote, gw4, out);
}

// Round 4
// 297.683 us; speedup vs baseline: 1.2591x; 1.2496x over previous
//
#include <hip/hip_runtime.h>
#include <hip/hip_bf16.h>

#define ADAPTERS 40
#define CAPS 3
#define IN_CH 600
#define BSZ 256
#define DCLS 200
#define DMODEL 768

typedef __attribute__((ext_vector_type(8))) short short8;   // 8 bf16
typedef __attribute__((ext_vector_type(4))) float f32x4;

// ---------------------------------------------------------------------------
// K0: gw4[j] = (g*lw[j][0], g*lw[j][1], g*lw[j][2], g*lb[j])
// ---------------------------------------------------------------------------
__global__ void k0_gw(const float* __restrict__ s_p,
                      const float* __restrict__ lw,
                      const float* __restrict__ lb,
                      const float* __restrict__ el,
                      const int* __restrict__ t_p,
                      float4* __restrict__ gw4) {
    int j = blockIdx.x * blockDim.x + threadIdx.x;
    if (j >= DMODEL) return;
    float s = s_p[0];
    int t = t_p[0];
    float e = el[t * DMODEL + j];
    float g = 1.0f / (1.0f + expf(-s * e));
    gw4[j] = make_float4(g * lw[j * 3 + 0], g * lw[j * 3 + 1],
                         g * lw[j * 3 + 2], g * lb[j]);
}

// ---------------------------------------------------------------------------
// K1 (MFMA): priors[cap][b][k][d] = sum_c x[b][k][c] * rw[k][cap][c][d]
// f32 inputs split into bf16 hi/lo; D += Ahi*Bhi + Ahi*Blo + Alo*Bhi
// (error ~2^-16 relative — f32-equivalent).
// Block = 128(b) x 128(j=cap*200+d padded to 640) of one adapter k.
// 4 waves; each wave a 64x64 sub-tile = 4x4 mfma_f32_16x16x32_bf16 tiles.
// K=600 in 19 chunks of 32 (tail zero-padded). Global loads for chunk+1
// issued before MFMA of chunk (software pipeline).
// ---------------------------------------------------------------------------
#define RP 40          // LDS row pitch in ushorts (32 data + 8 pad = 80 B)
#define NCHUNK 19

__device__ __forceinline__ void split2(float f0, float f1,
                                       unsigned& hi, unsigned& lo) {
    unsigned u0 = __float_as_uint(f0), u1 = __float_as_uint(f1);
    unsigned h0 = u0 & 0xFFFF0000u, h1 = u1 & 0xFFFF0000u;
    hi = (u0 >> 16) | h1;
    float l0 = f0 - __uint_as_float(h0);
    float l1 = f1 - __uint_as_float(h1);
    lo = (__float_as_uint(l0) >> 16) | (__float_as_uint(l1) & 0xFFFF0000u);
}

__global__ __launch_bounds__(256) void k1_priors(
    const float* __restrict__ x,    // [B][A][IN_CH]
    const float* __restrict__ rw,   // [A][CAPS][IN_CH][DCLS]
    const float* __restrict__ tsv,  // [A][A]
    const int* __restrict__ t_p,
    float* __restrict__ priors)     // [CAPS][B][A][DCLS]
{
    int kk = blockIdx.z;            // adapter
    int t = t_p[0];
    if (tsv[t * ADAPTERS + kk] == 0.0f) return;

    int b0 = blockIdx.x * 128;      // 0 or 128
    int j0 = blockIdx.y * 128;      // 0..512

    __shared__ __align__(16) unsigned short Ahi[128 * RP];
    __shared__ __align__(16) unsigned short Alo[128 * RP];
    __shared__ __align__(16) unsigned short Bhi[128 * RP];
    __shared__ __align__(16) unsigned short Blo[128 * RP];

    int tid = threadIdx.x;
    int lane = tid & 63, w = tid >> 6;
    int lm = lane & 15, lq = lane >> 4;
    int m0w = (w & 1) * 64, n0w = (w >> 1) * 64;

    // ---- staging thread maps ----
    // A: thread -> (bi = tid>>1, ci0 = (tid&1)*16), 4 float4 per chunk
    int a_bi = tid >> 1;
    int a_ci0 = (tid & 1) * 16;
    const float* a_row = x + ((size_t)(b0 + a_bi) * ADAPTERS + kk) * IN_CH;
    // B: thread -> (jj = tid>>1, ci0 = (tid&1)*16), 16 strided scalars
    int b_jj = tid >> 1;
    int b_ci0 = (tid & 1) * 16;
    int j = j0 + b_jj;
    bool jvalid = (j < CAPS * DCLS);
    int cap = (j >= 2 * DCLS) ? 2 : ((j >= DCLS) ? 1 : 0);
    int d = j - cap * DCLS;
    const float* b_base = rw + ((size_t)(kk * 3 + cap) * IN_CH) * DCLS + d;

    f32x4 acc[4][4];
    #pragma unroll
    for (int mt = 0; mt < 4; mt++)
        #pragma unroll
        for (int nt = 0; nt < 4; nt++)
            acc[mt][nt] = (f32x4){0.f, 0.f, 0.f, 0.f};

    float4 ax[4];
    float  bx[16];

    // prologue: load chunk 0
    {
        int c0 = 0;
        #pragma unroll
        for (int q = 0; q < 4; q++) {
            int c = c0 + a_ci0 + q * 4;
            ax[q] = (c + 4 <= IN_CH) ? *(const float4*)(a_row + c)
                                     : make_float4(0.f, 0.f, 0.f, 0.f);
        }
        #pragma unroll
        for (int i = 0; i < 16; i++) {
            int c = c0 + b_ci0 + i;
            bx[i] = (jvalid && c < IN_CH) ? b_base[(size_t)c * DCLS] : 0.f;
        }
    }

    for (int ch = 0; ch < NCHUNK; ch++) {
        // convert staged regs to hi/lo packed pairs
        unsigned ahi[8], alo[8], bhi[8], blo[8];
        #pragma unroll
        for (int q = 0; q < 4; q++) {
            split2(ax[q].x, ax[q].y, ahi[q * 2], alo[q * 2]);
            split2(ax[q].z, ax[q].w, ahi[q * 2 + 1], alo[q * 2 + 1]);
        }
        #pragma unroll
        for (int p = 0; p < 8; p++)
            split2(bx[2 * p], bx[2 * p + 1], bhi[p], blo[p]);

        __syncthreads();   // previous chunk's MFMA done reading LDS
        {
            unsigned* pa = (unsigned*)&Ahi[a_bi * RP + a_ci0];
            *(uint4*)pa = make_uint4(ahi[0], ahi[1], ahi[2], ahi[3]);
            *(uint4*)(pa + 4) = make_uint4(ahi[4], ahi[5], ahi[6], ahi[7]);
            unsigned* pl = (unsigned*)&Alo[a_bi * RP + a_ci0];
            *(uint4*)pl = make_uint4(alo[0], alo[1], alo[2], alo[3]);
            *(uint4*)(pl + 4) = make_uint4(alo[4], alo[5], alo[6], alo[7]);
            unsigned* pb = (unsigned*)&Bhi[b_jj * RP + b_ci0];
            *(uint4*)pb = make_uint4(bhi[0], bhi[1], bhi[2], bhi[3]);
            *(uint4*)(pb + 4) = make_uint4(bhi[4], bhi[5], bhi[6], bhi[7]);
            unsigned* pc = (unsigned*)&Blo[b_jj * RP + b_ci0];
            *(uint4*)pc = make_uint4(blo[0], blo[1], blo[2], blo[3]);
            *(uint4*)(pc + 4) = make_uint4(blo[4], blo[5], blo[6], blo[7]);
        }
        __syncthreads();

        // issue next chunk's global loads before compute
        if (ch + 1 < NCHUNK) {
            int c0 = (ch + 1) * 32;
            #pragma unroll
            for (int q = 0; q < 4; q++) {
                int c = c0 + a_ci0 + q * 4;
                ax[q] = (c + 4 <= IN_CH) ? *(const float4*)(a_row + c)
                                         : make_float4(0.f, 0.f, 0.f, 0.f);
            }
            #pragma unroll
            for (int i = 0; i < 16; i++) {
                int c = c0 + b_ci0 + i;
                bx[i] = (jvalid && c < IN_CH) ? b_base[(size_t)c * DCLS] : 0.f;
            }
        }

        // fragments + MFMA
        short8 Afh[4], Afl[4];
        #pragma unroll
        for (int mt = 0; mt < 4; mt++) {
            int row = m0w + mt * 16 + lm;
            Afh[mt] = *(const short8*)&Ahi[row * RP + lq * 8];
            Afl[mt] = *(const short8*)&Alo[row * RP + lq * 8];
        }
        #pragma unroll
        for (int nt = 0; nt < 4; nt++) {
            int row = n0w + nt * 16 + lm;
            short8 bh = *(const short8*)&Bhi[row * RP + lq * 8];
            short8 bl = *(const short8*)&Blo[row * RP + lq * 8];
            #pragma unroll
            for (int mt = 0; mt < 4; mt++) {
                acc[mt][nt] = __builtin_amdgcn_mfma_f32_16x16x32_bf16(
                    Afh[mt], bh, acc[mt][nt], 0, 0, 0);
                acc[mt][nt] = __builtin_amdgcn_mfma_f32_16x16x32_bf16(
                    Afh[mt], bl, acc[mt][nt], 0, 0, 0);
                acc[mt][nt] = __builtin_amdgcn_mfma_f32_16x16x32_bf16(
                    Afl[mt], bh, acc[mt][nt], 0, 0, 0);
            }
        }
    }

    // epilogue: C/D layout col=lane&15 (j), row=quad*4+reg (b)
    #pragma unroll
    for (int nt = 0; nt < 4; nt++) {
        int jc = j0 + n0w + nt * 16 + lm;
        if (jc >= CAPS * DCLS) continue;
        int capc = (jc >= 2 * DCLS) ? 2 : ((jc >= DCLS) ? 1 : 0);
        int dc = jc - capc * DCLS;
        #pragma unroll
        for (int mt = 0; mt < 4; mt++) {
            int bbase = b0 + m0w + mt * 16 + lq * 4;
            #pragma unroll
            for (int r = 0; r < 4; r++) {
                int b = bbase + r;
                priors[((size_t)(capc * BSZ + b) * ADAPTERS + kk) * DCLS + dc] =
                    acc[mt][nt][r];
            }
        }
    }
}

// ---------------------------------------------------------------------------
// K2: dynamic routing, one block per (n,b); P[k][d] staged in LDS.
// ---------------------------------------------------------------------------
__global__ __launch_bounds__(256) void k2_route(
    const float* __restrict__ priors,   // [CAPS][B][A][DCLS]
    const float* __restrict__ tsv,
    const int* __restrict__ t_p,
    float* __restrict__ vote)           // [CAPS][B][DCLS]
{
    int nb = blockIdx.x;
    int n = nb >> 8, b = nb & 255;
    int tid = threadIdx.x;
    int lane = tid & 63, wid = tid >> 6;

    __shared__ float Ps[ADAPTERS * DCLS];
    __shared__ float vout[DCLS];
    __shared__ float a_s[ADAPTERS];
    __shared__ float probs_s[ADAPTERS];
    __shared__ float act[ADAPTERS];
    __shared__ float red[4];
    __shared__ float scl;

    int t = t_p[0];
    if (tid < ADAPTERS) {
        act[tid] = tsv[t * ADAPTERS + tid];
        a_s[tid] = 0.0f;
    }
    __syncthreads();

    const float* pb = priors + (size_t)(n * BSZ + b) * ADAPTERS * DCLS;
    for (int idx = tid; idx < ADAPTERS * DCLS; idx += 256) {
        int k = idx / DCLS;
        if (act[k] != 0.0f) Ps[idx] = pb[idx];
    }
    __syncthreads();

    float cnt = 0.0f;
    for (int k = 0; k < ADAPTERS; k++) cnt += (act[k] != 0.f) ? 1.f : 0.f;

    int td = tid;
    float v = 0.0f;
    if (td < DCLS) {
        for (int k = 0; k < ADAPTERS; k++)
            if (act[k] != 0.f) v += Ps[k * DCLS + td];
        v /= cnt;
    }

    for (int it = 0; it < 3; it++) {
        if (it > 0) {
            if (wid == 0) {
                bool on = (lane < ADAPTERS) && (act[lane] != 0.f);
                float val = on ? a_s[lane] : -3.0e38f;
                float m = val;
                for (int off = 32; off; off >>= 1)
                    m = fmaxf(m, __shfl_down(m, off));
                m = __shfl(m, 0);
                float e = on ? expf(val - m) : 0.f;
                float ssum = e;
                for (int off = 32; off; off >>= 1)
                    ssum += __shfl_down(ssum, off);
                ssum = __shfl(ssum, 0);
                if (lane < ADAPTERS) probs_s[lane] = e / ssum;
            }
            __syncthreads();
            v = 0.0f;
            if (td < DCLS) {
                for (int k = 0; k < ADAPTERS; k++)
                    if (act[k] != 0.f) v += probs_s[k] * Ps[k * DCLS + td];
            }
        }
        if (it == 2) break;

        float vv = (td < DCLS) ? v * v : 0.f;
        for (int off = 32; off; off >>= 1) vv += __shfl_down(vv, off);
        if (lane == 0) red[wid] = vv;
        __syncthreads();
        if (tid == 0) {
            float sq = red[0] + red[1] + red[2] + red[3];
            scl = sqrtf(sq) / (1.0f + sq);
        }
        __syncthreads();
        if (td < DCLS) vout[td] = v * scl;
        __syncthreads();

        for (int k = wid; k < ADAPTERS; k += 4) {
            if (act[k] == 0.f) continue;
            const float* row = Ps + k * DCLS;
            float p = row[lane] * vout[lane]
                    + row[lane + 64] * vout[lane + 64]
                    + row[lane + 128] * vout[lane + 128];
            if (lane < DCLS - 192) p += row[lane + 192] * vout[lane + 192];
            for (int off = 32; off; off >>= 1) p += __shfl_down(p, off);
            if (lane == 0) a_s[k] += p;
        }
        __syncthreads();
    }

    if (td < DCLS) vote[(size_t)n * BSZ * DCLS + b * DCLS + td] = v;
}

// ---------------------------------------------------------------------------
// K3: out[row][j] = sum_c vote_flat[row*3+c]*gw4[j].c + gw4[j].w
// vote staged in LDS; nontemporal float4 stores (157 MB pure write stream).
// ---------------------------------------------------------------------------
typedef __attribute__((ext_vector_type(4))) float f4v;

__global__ __launch_bounds__(256) void k3_out(
    const float* __restrict__ vote,     // [3*256*200] flat
    const float4* __restrict__ gw4,     // [768]
    float* __restrict__ out)            // [51200][768]
{
    __shared__ float vs[192];
    int tid = threadIdx.x;
    int r0 = blockIdx.x * 64;
    if (tid < 192) vs[tid] = vote[r0 * 3 + tid];
    __syncthreads();

    int lane = tid & 63;
    int ty = tid >> 6;
    int j = blockIdx.y * 256 + lane * 4;

    float4 g0 = gw4[j + 0];
    float4 g1 = gw4[j + 1];
    float4 g2 = gw4[j + 2];
    float4 g3 = gw4[j + 3];

    #pragma unroll
    for (int it = 0; it < 16; it++) {
        int rl = it * 4 + ty;
        float h0 = vs[rl * 3 + 0];
        float h1 = vs[rl * 3 + 1];
        float h2 = vs[rl * 3 + 2];
        f4v o;
        o.x = h0 * g0.x + h1 * g0.y + h2 * g0.z + g0.w;
        o.y = h0 * g1.x + h1 * g1.y + h2 * g1.z + g1.w;
        o.z = h0 * g2.x + h1 * g2.y + h2 * g2.z + g2.w;
        o.w = h0 * g3.x + h1 * g3.y + h2 * g3.z + g3.w;
        __builtin_nontemporal_store(o, (f4v*)(out + (size_t)(r0 + rl) * DMODEL + j));
    }
}

// ---------------------------------------------------------------------------
extern "C" void kernel_launch(void* const* d_in, const int* in_sizes, int n_in,
                              void* d_out, int out_size, void* d_ws, size_t ws_size,
                              hipStream_t stream) {
    const int*   t   = (const int*)d_in[0];
    const float* x   = (const float*)d_in[1];
    const float* s   = (const float*)d_in[2];
    const float* rw  = (const float*)d_in[3];
    const float* lw  = (const float*)d_in[4];
    const float* lb  = (const float*)d_in[5];
    const float* el  = (const float*)d_in[6];
    const float* tsv = (const float*)d_in[7];
    float* out = (float*)d_out;

    char* wsb = (char*)d_ws;
    float*  priors = (float*)wsb;                // 24,576,000 B
    float*  vote   = (float*)(wsb + 24576000);   // 614,400 B
    float4* gw4    = (float4*)(wsb + 25190400);  // 12,288 B

    k0_gw<<<dim3(3), dim3(256), 0, stream>>>(s, lw, lb, el, t, gw4);
    k1_priors<<<dim3(2, 5, ADAPTERS), dim3(256), 0, stream>>>(x, rw, tsv, t, priors);
    k2_route<<<dim3(CAPS * BSZ), dim3(256), 0, stream>>>(priors, tsv, t, vote);
    k3_out<<<dim3(BSZ * DCLS / 64, 3), dim3(256), 0, stream>>>(vote, gw4, out);
}